// Round 8
// baseline (560.710 us; speedup 1.0000x reference)
//
#include <hip/hip_runtime.h>
#include <math.h>

// HGPSLPool: B=64 graphs, N=1024 nodes, D=128, EPG=8192, K=820.
// Outputs (concat, float32 view): feat_p [B*K*D], weights [B*K*K], perm [B*K], x_score [NTOT].

static constexpr int B_    = 64;
static constexpr int N_    = 1024;
static constexpr int D_    = 128;
static constexpr int NTOT_ = B_ * N_;     // 65536
static constexpr int ETOT_ = B_ * 8192;   // 524288
static constexpr int K_    = 820;
static constexpr int BK_   = B_ * K_;     // 52480
static constexpr float NEG_ = 0.2f;
static constexpr int CH_   = 128;         // k_tau: columns per block
static constexpr int CPB_  = 7;           // chunks per graph (7*128=896 >= 820)
static constexpr int CAP_  = 64;          // k_agg: staged edges per node (max in-deg ~30)
static constexpr int NDED_ = (BK_ + 511) / 512;   // 103 dedupe blocks @512

__device__ __forceinline__ float lrelu(float x) { return x >= 0.f ? x : NEG_ * x; }

// ---- fused: blocks [0,2048) degrees; block 2048 computes wa = W@a ----
__global__ void k_wa_deg(const float* __restrict__ W, const float* __restrict__ a,
                         float* __restrict__ waf, const int* __restrict__ src,
                         const int* __restrict__ dst, int* __restrict__ outd,
                         int* __restrict__ ind) {
  int g = blockIdx.x, t = threadIdx.x;
  if (g < 2048) {
    int e = g * 256 + t;
    atomicAdd(&outd[src[e]], 1);
    atomicAdd(&ind[dst[e]], 1);
  } else if (t < 128) {
    double s = 0.0;
    for (int k = 0; k < D_; ++k) s += (double)W[t * D_ + k] * (double)a[k];
    waf[t] = (float)s;
  }
}

// ---- single-dispatch exclusive scan: each block sums its preceding region ----
__global__ void k_scan1(const int* __restrict__ in, int n, int* __restrict__ out) {
  int blk = blockIdx.x, t = threadIdx.x;
  int w = t >> 6, lane = t & 63;
  __shared__ int sbase;
  __shared__ int wred[4];
  __shared__ int wtot[4];
  int pre = blk * 1024;                 // sum in[0, pre)
  int s0 = 0;
  for (int i = t; i < pre; i += 256) s0 += in[i];
#pragma unroll
  for (int off = 32; off > 0; off >>= 1) s0 += __shfl_down(s0, off);
  if (lane == 0) wred[w] = s0;
  __syncthreads();
  if (t == 0) sbase = wred[0] + wred[1] + wred[2] + wred[3];
  int base = pre + t * 4;
  int a0 = (base < n) ? in[base] : 0;
  int a1 = (base + 1 < n) ? in[base + 1] : 0;
  int a2 = (base + 2 < n) ? in[base + 2] : 0;
  int a3 = (base + 3 < n) ? in[base + 3] : 0;
  int s = a0 + a1 + a2 + a3;
  int inc = s;
#pragma unroll
  for (int off = 1; off < 64; off <<= 1) {
    int vv = __shfl_up(inc, off);
    if (lane >= off) inc += vv;
  }
  if (lane == 63) wtot[w] = inc;
  __syncthreads();
  int wbase = 0;
  for (int q = 0; q < w; ++q) wbase += wtot[q];
  int ex = sbase + wbase + inc - s;
  if (base < n) out[base] = ex; ex += a0;
  if (base + 1 < n) out[base + 1] = ex; ex += a1;
  if (base + 2 < n) out[base + 2] = ex; ex += a2;
  if (base + 3 < n) out[base + 3] = ex; ex += a3;
  if (blk == (int)gridDim.x - 1 && t == 255) out[n] = ex;   // grand total
}

// ---- fill dst-CSR ----
__global__ void k_fillcsr(const int* __restrict__ dst, const int* __restrict__ rowptr,
                          int* __restrict__ cursor, int* __restrict__ col) {
  int e = blockIdx.x * 256 + threadIdx.x;
  int v = dst[e];
  int p = atomicAdd(&cursor[v], 1);
  col[rowptr[v] + p] = e;
}

// ---- neighbor aggregation + info + attn + x_score ----
// float4 lanes: wave = 2 halves x 32 lanes; lane handles 16B of one of two edges
// per iteration (half the VMEM instrs, 2 rows in flight per issue). Zero-padded
// LDS edge table kills tail branches. XCD swizzle keeps per-XCD feat set ~ L2.
__global__ void k_agg(const float* __restrict__ feat, const float* __restrict__ e_feat,
                      const int* __restrict__ src, const int* __restrict__ col,
                      const int* __restrict__ rowptr, const int* __restrict__ outd,
                      const int* __restrict__ ind, const float* __restrict__ waf,
                      float* __restrict__ out_xs) {
  __shared__ int su[4][CAP_];
  __shared__ float ssc[4][CAP_];
  int g = blockIdx.x;
  int vb = (g & 7) * 2048 + (g >> 3);           // 16384 blocks / 8 XCDs
  int w = threadIdx.x >> 6, lane = threadIdx.x & 63;
  int hd = lane >> 5, li = lane & 31;
  int v = vb * 4 + w;
  int r0 = rowptr[v], r1 = rowptr[v + 1];
  int m = r1 - r0;
  int mm = m < CAP_ ? m : CAP_;
  for (int s = lane; s < CAP_; s += 64) { su[w][s] = 0; ssc[w][s] = 0.f; }
  for (int s = lane; s < mm; s += 64) {
    int e = col[r0 + s];
    int u = src[e];
    float sc = (u == v) ? 0.f : e_feat[e] / sqrtf(fmaxf((float)outd[u], 1.f));
    su[w][s] = u;
    ssc[w][s] = sc;
  }
  __syncthreads();
  const float4* f4 = (const float4*)feat;
  float ax = 0.f, ay = 0.f, az = 0.f, aw = 0.f;
  int mmp = (mm + 3) & ~3;                      // <= CAP_
  for (int s = 0; s < mmp; s += 4) {            // 4 edges per wave-iter, 2 loads/lane
    int e0 = s + hd, e1 = s + 2 + hd;
    int u0 = su[w][e0], u1 = su[w][e1];
    float c0 = ssc[w][e0], c1 = ssc[w][e1];
    float4 fa = f4[(size_t)u0 * 32 + li];
    float4 fb = f4[(size_t)u1 * 32 + li];
    ax += fa.x * c0 + fb.x * c1;
    ay += fa.y * c0 + fb.y * c1;
    az += fa.z * c0 + fb.z * c1;
    aw += fa.w * c0 + fb.w * c1;
  }
  for (int sP = r0 + CAP_; sP < r1; ++sP) {     // statistically never taken
    if (hd) break;
    int e = col[sP];
    int u = src[e];
    if (u == v) continue;
    float sc = e_feat[e] / sqrtf(fmaxf((float)outd[u], 1.f));
    float4 fu = f4[(size_t)u * 32 + li];
    ax += fu.x * sc; ay += fu.y * sc; az += fu.z * sc; aw += fu.w * sc;
  }
  // combine the two halves (each dim then present in both halves)
  ax += __shfl_xor(ax, 32); ay += __shfl_xor(ay, 32);
  az += __shfl_xor(az, 32); aw += __shfl_xor(aw, 32);
  float4 fv = f4[(size_t)v * 32 + li];
  float4 wv = ((const float4*)waf)[li];
  float dn = 1.f / sqrtf(fmaxf((float)ind[v], 1.f));
  float info = fabsf(fv.x - ax * dn) + fabsf(fv.y - ay * dn)
             + fabsf(fv.z - az * dn) + fabsf(fv.w - aw * dn);
  float dot = fv.x * wv.x + fv.y * wv.y + fv.z * wv.z + fv.w * wv.w;
#pragma unroll
  for (int off = 16; off > 0; off >>= 1) {      // width-32 reduce (one half only)
    info += __shfl_down(info, off, 32);
    dot  += __shfl_down(dot, off, 32);
  }
  if (lane == 0) {
    float sA = dot >= 0.f ? dot : 0.2f * dot;   // leaky_relu 0.2
    float attn = 1.f / (1.f + expf(-sA));
    out_xs[v] = info * attn;
  }
}

// ---- per-graph top-K: bitonic sort of u64-packed (f32 value desc, idx asc) ----
__global__ void k_topk(const float* __restrict__ xs, float* __restrict__ out_perm,
                       int* __restrict__ perm_i, int* __restrict__ maskarr) {
  __shared__ unsigned long long dv[1024];
  int b = blockIdx.x, t = threadIdx.x;
  for (int i = t; i < 1024; i += 512) {
    unsigned bits = __float_as_uint(xs[b * 1024 + i]);
    dv[i] = ((unsigned long long)bits << 32) | (unsigned)(N_ - 1 - i);
  }
  __syncthreads();
  for (int k2 = 2; k2 <= 1024; k2 <<= 1) {
    for (int j = k2 >> 1; j > 0; j >>= 1) {
      for (int i = t; i < 1024; i += 512) {
        int ixj = i ^ j;
        if (ixj > i) {
          unsigned long long a = dv[i], c = dv[ixj];
          bool dir = ((i & k2) == 0);
          if ((a > c) != dir) { dv[i] = c; dv[ixj] = a; }
        }
      }
      __syncthreads();
    }
  }
  for (int r = t; r < K_; r += 512) {
    int idx = N_ - 1 - (int)(dv[r] & 0xFFFFFFFFull);
    int node = b * N_ + idx;
    int pos = b * K_ + r;
    out_perm[pos] = (float)node;    // output buffer is float32 view
    perm_i[pos] = node;
    maskarr[node] = pos;
  }
}

// ---- fused: blocks [0,13120) gather feat_p + wsrc/wdst; [13120,15168) cnt2 ----
__global__ void k_gather_cnt2(const float* __restrict__ feat,
                              const int* __restrict__ perm_i,
                              const float* __restrict__ att,
                              float* __restrict__ out_featp,
                              float* __restrict__ wsrc, float* __restrict__ wdst,
                              const int* __restrict__ src, const int* __restrict__ dst,
                              const int* __restrict__ maskarr, int* __restrict__ cnt2) {
  int g = blockIdx.x;
  if (g >= 13120) {
    int e = (g - 13120) * 256 + threadIdx.x;
    int nr = maskarr[src[e]], nc = maskarr[dst[e]];
    if (nr >= 0 && nc >= 0) atomicAdd(&cnt2[nc], 1);
    return;
  }
  int vb = (g & 7) * 1640 + (g >> 3);           // 13120 / 8
  int gid = vb * 256 + threadIdx.x;
  int p = gid >> 6, lane = gid & 63;
  int node = perm_i[p];
  float2 f = ((const float2*)feat)[(size_t)node * 64 + lane];
  ((float2*)out_featp)[(size_t)p * 64 + lane] = f;
  float s1 = f.x * att[2 * lane] + f.y * att[2 * lane + 1];
  float s2 = f.x * att[D_ + 2 * lane] + f.y * att[D_ + 2 * lane + 1];
#pragma unroll
  for (int off = 32; off > 0; off >>= 1) {
    s1 += __shfl_down(s1, off);
    s2 += __shfl_down(s2, off);
  }
  if (lane == 0) { wsrc[p] = s1; wdst[p] = s2; }
}

__global__ void k_fill2(const int* __restrict__ src, const int* __restrict__ dst,
                        const int* __restrict__ maskarr, const float* __restrict__ e_feat,
                        const int* __restrict__ rowptr2, int* __restrict__ cursor2,
                        int* __restrict__ colii, float* __restrict__ colval) {
  int e = blockIdx.x * 256 + threadIdx.x;
  int nr = maskarr[src[e]], nc = maskarr[dst[e]];
  if (nr >= 0 && nc >= 0) {
    int p = atomicAdd(&cursor2[nc], 1);
    int s = rowptr2[nc] + p;
    colii[s] = nr;                 // global pooled src index (b*K + i)
    colval[s] = 1.0f * e_feat[e];  // LAMB = 1
  }
}

// ---- fused: blocks [0,NDED_) dedupe+pre-gather; [NDED_,NDED_+64) per-graph sort ----
__global__ void k_ded_gsort(const int* __restrict__ rowptr2, int* __restrict__ colii,
                            float* __restrict__ colval, int* __restrict__ ucnt,
                            const float* __restrict__ wsrc, float2* __restrict__ bval,
                            float* __restrict__ ws_sorted, float* __restrict__ psum) {
  int g = blockIdx.x, t = threadIdx.x;
  if (g < NDED_) {
    int c = g * 512 + t;
    if (c >= BK_) return;
    int r0 = rowptr2[c], r1 = rowptr2[c + 1];
    int w = r0;
    for (int s = r0; s < r1; ++s) {
      int ii = colii[s];
      if (ii < 0) continue;
      float E = colval[s];
      for (int t2 = s + 1; t2 < r1; ++t2)
        if (colii[t2] == ii) { E += colval[t2]; colii[t2] = -1; }
      colii[w] = ii; colval[w] = E; ++w;
    }
    ucnt[c] = w - r0;
    for (int s = r0; s < w; ++s) bval[s] = make_float2(wsrc[colii[s]], colval[s]);
    return;
  }
  __shared__ float sv[1024];
  __shared__ float sc[1024];
  int b = g - NDED_;
  for (int i = t; i < 1024; i += 512) sv[i] = (i < K_) ? wsrc[b * K_ + i] : -INFINITY;
  __syncthreads();
  for (int k2 = 2; k2 <= 1024; k2 <<= 1) {
    for (int j = k2 >> 1; j > 0; j >>= 1) {
      for (int i = t; i < 1024; i += 512) {
        int ixj = i ^ j;
        if (ixj > i) {
          float a = sv[i], c = sv[ixj];
          bool dir = ((i & k2) == 0);
          bool swapv = dir ? (c > a) : (a > c);
          if (swapv) { sv[i] = c; sv[ixj] = a; }
        }
      }
      __syncthreads();
    }
  }
  for (int i = t; i < 1024; i += 512) { ws_sorted[b * 1024 + i] = sv[i]; sc[i] = sv[i]; }
  __syncthreads();
  for (int off = 1; off < 1024; off <<= 1) {
    float tmp[2];
    for (int i = t, q = 0; i < 1024; i += 512, ++q) tmp[q] = (i >= off) ? sc[i - off] : 0.f;
    __syncthreads();
    for (int i = t, q = 0; i < 1024; i += 512, ++q) sc[i] += tmp[q];
    __syncthreads();
  }
  if (t == 0) psum[b * 1025] = 0.f;
  for (int i = t; i < 1024; i += 512) psum[b * 1025 + 1 + i] = sc[i];
}

// count of entries > thr in desc-sorted LDS array, searching index range [lo,hi)
__device__ __forceinline__ int cnt_gt_rng(const float* __restrict__ arr, float thr,
                                          int lo, int hi) {
  while (lo < hi) {
    int mid = (lo + hi) >> 1;
    if (arr[mid] > thr) lo = mid + 1; else hi = mid;
  }
  return lo;
}

// ---- tau per column via bisection on g(t) = sum max(z-t,0) = 1 ----
__global__ void __launch_bounds__(128) k_tau(
    const float* __restrict__ wdst,
    const float* __restrict__ ws_sorted, const float* __restrict__ psum,
    const int* __restrict__ rowptr2, const int* __restrict__ ucnt,
    const float2* __restrict__ bval, float* __restrict__ tauv) {
  __shared__ float swss[1024];
  __shared__ float sps[1025];
  int b = blockIdx.x / CPB_;
  int chunk = blockIdx.x % CPB_;
  int t0 = threadIdx.x;
  for (int i = t0; i < 1024; i += 128) swss[i] = ws_sorted[b * 1024 + i];
  for (int i = t0; i < 1025; i += 128) sps[i] = psum[b * 1025 + i];
  __syncthreads();

  int j = chunk * CH_ + t0;
  if (j >= K_) return;
  int c = b * K_ + j;

  float wd = wdst[c];
  int p = cnt_gt_rng(swss, -wd, 0, K_);
  float psp = sps[p];
  int r0 = rowptr2[c], m = ucnt[c];

  float mz = lrelu(swss[0] + wd);
  for (int s = 0; s < m; ++s) {
    float2 v = bval[r0 + s];
    mz = fmaxf(mz, lrelu(v.x + wd) + v.y);       // E > 0 (e_feat=1, LAMB=1)
  }

  float lo = mz - 1.0f, hi = mz;                 // g(mz)=0<1, g(mz-1)>=1
  int nmin = 0, nmax = K_;                       // support-count bracket
  for (int it = 0; it < 22; ++it) {
    float t = 0.5f * (lo + hi);
    float wthr = (t >= 0.f ? t : 5.f * t) - wd;
    int n = cnt_gt_rng(swss, wthr, nmin, nmax);
    float bsum = (n <= p) ? (sps[n] + n * wd)
                          : (psp + p * wd + NEG_ * (sps[n] - psp + (n - p) * wd));
    float g = bsum - n * t;
    for (int s = 0; s < m; ++s) {
      float2 v = bval[r0 + s];
      float bse = lrelu(v.x + wd);
      g += fmaxf(bse + v.y - t, 0.f) - fmaxf(bse - t, 0.f);
    }
    if (g > 1.f) { lo = t; nmax = n; } else { hi = t; nmin = n; }
  }
  float t = lo;                                  // t <= tau*, bracket ~2.4e-7
  float wthr = (t >= 0.f ? t : 5.f * t) - wd;
  int n = cnt_gt_rng(swss, wthr, nmin, nmax);
  float S = (n <= p) ? (sps[n] + n * wd)
                     : (psp + p * wd + NEG_ * (sps[n] - psp + (n - p) * wd));
  int cc = n;
  for (int s = 0; s < m; ++s) {
    float2 v = bval[r0 + s];
    float bse = lrelu(v.x + wd);
    float zz = bse + v.y;
    if (v.x > wthr) { S -= bse; cc -= 1; }       // same predicate as cnt -> exact cancel
    if (zz > t)     { S += zz;  cc += 1; }
  }
  float tau = (cc < 1) ? (mz - 1.0f) : ((S - 1.0f) / (float)cc);
  tau = fminf(fmaxf(tau, mz - 1.0f), mz);        // true tau* in [mz-1, mz)
  tauv[c] = tau;
}

// ---- dense weights: float4 per thread (820 = 205*4), coalesced dwordx4 ----
__global__ void k_dense(const float* __restrict__ wsrc, const float* __restrict__ wdst,
                        const float* __restrict__ tauv, float* __restrict__ out_w) {
  int t = threadIdx.x;
  int j4 = t * 4;
  if (j4 >= K_) return;
  int row = blockIdx.x;                         // b*K + i
  int b = row / K_;
  const float4* wd4 = (const float4*)(wdst + b * K_);
  const float4* ta4 = (const float4*)(tauv + b * K_);
  float ws = wsrc[row];
  float4 wd = wd4[t];
  float4 ta = ta4[t];
  float4 o;
  float z;
  z = lrelu(ws + wd.x) - ta.x; o.x = (z > 1e-9f) ? z : 0.f;
  z = lrelu(ws + wd.y) - ta.y; o.y = (z > 1e-9f) ? z : 0.f;
  z = lrelu(ws + wd.z) - ta.z; o.z = (z > 1e-9f) ? z : 0.f;
  z = lrelu(ws + wd.w) - ta.w; o.w = (z > 1e-9f) ? z : 0.f;
  ((float4*)(out_w + (size_t)row * K_))[t] = o;
}

// ---- rewrite the edge-perturbed entries with the correct value ----
__global__ void k_fix(const float* __restrict__ wsrc, const float* __restrict__ wdst,
                      const float* __restrict__ tauv, const int* __restrict__ rowptr2,
                      const int* __restrict__ ucnt, const int* __restrict__ colii,
                      const float* __restrict__ colval, float* __restrict__ out_w) {
  int c = blockIdx.x * 256 + threadIdx.x;
  int b = c / K_;
  int j = c - b * K_;
  float wd = wdst[c], ta = tauv[c];
  int r0 = rowptr2[c], m = ucnt[c];
  for (int s = 0; s < m; ++s) {
    int nr = colii[r0 + s];
    float z = lrelu(wsrc[nr] + wd) + colval[r0 + s];
    float v = z - ta;
    out_w[(size_t)nr * K_ + j] = (v > 1e-9f) ? v : 0.f;
  }
}

extern "C" void kernel_launch(void* const* d_in, const int* in_sizes, int n_in,
                              void* d_out, int out_size, void* d_ws, size_t ws_size,
                              hipStream_t stream) {
  const float* feat   = (const float*)d_in[0];
  const float* e_feat = (const float*)d_in[1];
  const float* W      = (const float*)d_in[2];
  const float* a      = (const float*)d_in[3];
  const float* att    = (const float*)d_in[4];
  const int*   src    = (const int*)d_in[5];
  const int*   dst    = (const int*)d_in[6];

  float* out_featp = (float*)d_out;                       // [BK*D]
  float* out_w     = out_featp + (size_t)BK_ * D_;        // [BK*K]
  float* out_perm  = out_w + (size_t)BK_ * K_;            // [BK]
  float* out_xs    = out_perm + BK_;                      // [NTOT]

  char* wsp = (char*)d_ws;
  auto carve = [&](size_t bytes) -> void* {
    void* pp = (void*)wsp;
    wsp += (bytes + 255) & ~(size_t)255;
    return pp;
  };
  float* waf       = (float*)carve((size_t)D_ * 4);
  float* wsrc      = (float*)carve((size_t)BK_ * 4);
  float* wdst      = (float*)carve((size_t)BK_ * 4);
  float* tauv      = (float*)carve((size_t)BK_ * 4);
  float* colval    = (float*)carve((size_t)ETOT_ * 4);
  float2* bval     = (float2*)carve((size_t)ETOT_ * 8);
  float* ws_sorted = (float*)carve((size_t)B_ * 1024 * 4);
  float* psum      = (float*)carve((size_t)B_ * 1025 * 4);
  int* rowptr      = (int*)carve((size_t)(NTOT_ + 1) * 4);
  int* rowptr2     = (int*)carve((size_t)(BK_ + 1) * 4);
  int* col         = (int*)carve((size_t)ETOT_ * 4);
  int* colii       = (int*)carve((size_t)ETOT_ * 4);
  int* perm_i      = (int*)carve((size_t)BK_ * 4);
  size_t zbytes    = ((size_t)NTOT_ * 3 + (size_t)BK_ * 2) * 4;
  int* zblk        = (int*)carve(zbytes);
  int* in_deg      = zblk;
  int* out_deg     = zblk + NTOT_;
  int* cursor      = zblk + 2 * NTOT_;
  int* cnt2        = zblk + 3 * NTOT_;
  int* cursor2     = cnt2 + BK_;
  int* maskarr     = (int*)carve((size_t)NTOT_ * 4);

  hipMemsetAsync(zblk, 0, zbytes, stream);
  hipMemsetAsync(maskarr, 0xFF, (size_t)NTOT_ * 4, stream);   // -1

  const int nbA = (NTOT_ + 1023) / 1024;   // 64
  const int nbB = (BK_ + 1023) / 1024;     // 52

  k_wa_deg<<<2049, 256, 0, stream>>>(W, a, waf, src, dst, out_deg, in_deg);
  k_scan1<<<nbA, 256, 0, stream>>>(in_deg, NTOT_, rowptr);
  k_fillcsr<<<ETOT_ / 256, 256, 0, stream>>>(dst, rowptr, cursor, col);
  k_agg<<<NTOT_ / 4, 256, 0, stream>>>(feat, e_feat, src, col, rowptr, out_deg, in_deg,
                                       waf, out_xs);
  k_topk<<<B_, 512, 0, stream>>>(out_xs, out_perm, perm_i, maskarr);
  k_gather_cnt2<<<13120 + 2048, 256, 0, stream>>>(feat, perm_i, att, out_featp,
                                                  wsrc, wdst, src, dst, maskarr, cnt2);
  k_scan1<<<nbB, 256, 0, stream>>>(cnt2, BK_, rowptr2);
  k_fill2<<<ETOT_ / 256, 256, 0, stream>>>(src, dst, maskarr, e_feat, rowptr2, cursor2,
                                           colii, colval);
  k_ded_gsort<<<NDED_ + B_, 512, 0, stream>>>(rowptr2, colii, colval, cursor2, wsrc,
                                              bval, ws_sorted, psum);
  k_tau<<<B_ * CPB_, 128, 0, stream>>>(wdst, ws_sorted, psum, rowptr2, cursor2,
                                       bval, tauv);
  k_dense<<<BK_, 256, 0, stream>>>(wsrc, wdst, tauv, out_w);
  k_fix<<<BK_ / 256, 256, 0, stream>>>(wsrc, wdst, tauv, rowptr2, cursor2, colii, colval,
                                       out_w);
}

// Round 9
// 556.323 us; speedup vs baseline: 1.0079x; 1.0079x over previous
//
#include <hip/hip_runtime.h>
#include <math.h>

// HGPSLPool: B=64 graphs, N=1024 nodes, D=128, EPG=8192, K=820.
// Outputs (concat, float32 view): feat_p [B*K*D], weights [B*K*K], perm [B*K], x_score [NTOT].

static constexpr int B_    = 64;
static constexpr int N_    = 1024;
static constexpr int D_    = 128;
static constexpr int NTOT_ = B_ * N_;     // 65536
static constexpr int ETOT_ = B_ * 8192;   // 524288
static constexpr int K_    = 820;
static constexpr int BK_   = B_ * K_;     // 52480
static constexpr float NEG_ = 0.2f;
static constexpr int CH_   = 128;         // k_tau: columns per block
static constexpr int CPB_  = 7;           // chunks per graph (7*128=896 >= 820)
static constexpr int CAP_  = 64;          // k_agg: staged edges per node (max in-deg ~30)
static constexpr int ST_   = 48;          // per-column sparse-entry stride (max in-deg ~30)

__device__ __forceinline__ float lrelu(float x) { return x >= 0.f ? x : NEG_ * x; }

// ---- wa = W @ a (fp64 accumulate, fp32 out), 1 block x 128 ----
__global__ void k_wa(const float* __restrict__ W, const float* __restrict__ a,
                     float* __restrict__ waf) {
  int d = threadIdx.x;
  double s = 0.0;
  for (int k = 0; k < D_; ++k) s += (double)W[d * D_ + k] * (double)a[k];
  waf[d] = (float)s;
}

// ---- degrees (self-loops included, matching ref) ----
__global__ void k_deg(const int* __restrict__ src, const int* __restrict__ dst,
                      int* __restrict__ outd, int* __restrict__ ind) {
  int e = blockIdx.x * 256 + threadIdx.x;
  atomicAdd(&outd[src[e]], 1);
  atomicAdd(&ind[dst[e]], 1);
}

// ---- parallel exclusive scan, phase 1: per-block (1024-elem chunk) sums ----
__global__ void k_scansum(const int* __restrict__ in, int n, int* __restrict__ bsum) {
  int blk = blockIdx.x, t = threadIdx.x;
  int base = blk * 1024 + t * 4;
  int s = 0;
#pragma unroll
  for (int q = 0; q < 4; ++q) { int i = base + q; if (i < n) s += in[i]; }
#pragma unroll
  for (int off = 32; off > 0; off >>= 1) s += __shfl_down(s, off);
  __shared__ int ws[4];
  int w = t >> 6, lane = t & 63;
  if (lane == 0) ws[w] = s;
  __syncthreads();
  if (t == 0) bsum[blk] = ws[0] + ws[1] + ws[2] + ws[3];
}

// ---- phase 2: block-local exscan + base from <=64 block sums; writes out[n] too ----
__global__ void k_scanout(const int* __restrict__ in, int n,
                          const int* __restrict__ bsum, int* __restrict__ out) {
  int blk = blockIdx.x, t = threadIdx.x;
  int w = t >> 6, lane = t & 63;
  __shared__ int sbase;
  __shared__ int wtot[4];
  if (w == 0) {                       // block base = sum of bsum[0..blk)  (grid <= 64)
    int v = (lane < blk) ? bsum[lane] : 0;
#pragma unroll
    for (int off = 32; off > 0; off >>= 1) v += __shfl_down(v, off);
    if (lane == 0) sbase = v;
  }
  int base = blk * 1024 + t * 4;
  int a0 = (base < n) ? in[base] : 0;
  int a1 = (base + 1 < n) ? in[base + 1] : 0;
  int a2 = (base + 2 < n) ? in[base + 2] : 0;
  int a3 = (base + 3 < n) ? in[base + 3] : 0;
  int s = a0 + a1 + a2 + a3;
  int inc = s;
#pragma unroll
  for (int off = 1; off < 64; off <<= 1) {
    int vv = __shfl_up(inc, off);
    if (lane >= off) inc += vv;
  }
  if (lane == 63) wtot[w] = inc;
  __syncthreads();
  int wbase = 0;
  for (int q = 0; q < w; ++q) wbase += wtot[q];
  int ex = sbase + wbase + inc - s;   // exclusive prefix for this thread's first elem
  if (base < n) out[base] = ex; ex += a0;
  if (base + 1 < n) out[base + 1] = ex; ex += a1;
  if (base + 2 < n) out[base + 2] = ex; ex += a2;
  if (base + 3 < n) out[base + 3] = ex; ex += a3;
  if (blk == (int)gridDim.x - 1 && t == 255) out[n] = ex;   // grand total
}

// ---- fill dst-CSR ----
__global__ void k_fillcsr(const int* __restrict__ dst, const int* __restrict__ rowptr,
                          int* __restrict__ cursor, int* __restrict__ col) {
  int e = blockIdx.x * 256 + threadIdx.x;
  int v = dst[e];
  int p = atomicAdd(&cursor[v], 1);
  col[rowptr[v] + p] = e;
}

// ---- neighbor aggregation + info + attn + x_score (fp32, 4-way gather ILP) ----
// XCD-aware swizzle: with round-robin block->XCD dispatch, vb=(g&7)*2048+(g>>3)
// gives XCD x exactly graphs [8x,8x+8) -> per-XCD feat working set = 4MB = L2.
__global__ void k_agg(const float* __restrict__ feat, const float* __restrict__ e_feat,
                      const int* __restrict__ src, const int* __restrict__ col,
                      const int* __restrict__ rowptr, const int* __restrict__ outd,
                      const int* __restrict__ ind, const float* __restrict__ waf,
                      float* __restrict__ out_xs) {
  __shared__ int su[4][CAP_];
  __shared__ float ssc[4][CAP_];
  int g = blockIdx.x;
  int vb = (g & 7) * 2048 + (g >> 3);           // 16384 blocks / 8 XCDs
  int w = threadIdx.x >> 6, lane = threadIdx.x & 63;
  int v = vb * 4 + w;
  int r0 = rowptr[v], r1 = rowptr[v + 1];
  int m = r1 - r0;
  int mm = m < CAP_ ? m : CAP_;
  for (int s = lane; s < mm; s += 64) {
    int e = col[r0 + s];
    int u = src[e];
    float sc = (u == v) ? 0.f : e_feat[e] / sqrtf(fmaxf((float)outd[u], 1.f));
    su[w][s] = u;
    ssc[w][s] = sc;
  }
  __syncthreads();
  const float2* f2 = (const float2*)feat;
  float2 f = f2[(size_t)v * 64 + lane];
  float ax = 0.f, ay = 0.f;
  int s = 0;
  for (; s + 4 <= mm; s += 4) {       // 4 independent 512B gathers in flight
    int u0 = su[w][s], u1 = su[w][s + 1], u2 = su[w][s + 2], u3 = su[w][s + 3];
    float c0 = ssc[w][s], c1 = ssc[w][s + 1], c2 = ssc[w][s + 2], c3 = ssc[w][s + 3];
    float2 f0 = f2[(size_t)u0 * 64 + lane];
    float2 f1 = f2[(size_t)u1 * 64 + lane];
    float2 fq = f2[(size_t)u2 * 64 + lane];
    float2 f3 = f2[(size_t)u3 * 64 + lane];
    ax += f0.x * c0 + f1.x * c1 + fq.x * c2 + f3.x * c3;
    ay += f0.y * c0 + f1.y * c1 + fq.y * c2 + f3.y * c3;
  }
  for (; s < mm; ++s) {
    float2 fu = f2[(size_t)su[w][s] * 64 + lane];
    ax += fu.x * ssc[w][s];
    ay += fu.y * ssc[w][s];
  }
  for (int sP = r0 + CAP_; sP < r1; ++sP) {     // statistically never taken
    int e = col[sP];
    int u = src[e];
    if (u == v) continue;
    float sc = e_feat[e] / sqrtf(fmaxf((float)outd[u], 1.f));
    float2 fu = f2[(size_t)u * 64 + lane];
    ax += fu.x * sc;
    ay += fu.y * sc;
  }
  float dn = 1.f / sqrtf(fmaxf((float)ind[v], 1.f));
  float info = fabsf(f.x - ax * dn) + fabsf(f.y - ay * dn);
  float dot = f.x * waf[2 * lane] + f.y * waf[2 * lane + 1];
#pragma unroll
  for (int off = 32; off > 0; off >>= 1) {
    info += __shfl_down(info, off);
    dot  += __shfl_down(dot, off);
  }
  if (lane == 0) {
    float sA = dot >= 0.f ? dot : 0.2f * dot;   // leaky_relu 0.2
    float attn = 1.f / (1.f + expf(-sA));
    out_xs[v] = info * attn;
  }
}

// ---- per-graph top-K: bitonic sort of u64-packed (f32 value desc, idx asc) ----
// x >= 0 so IEEE bits order == numeric order. key = (bits<<32) | (N-1-idx).
__global__ void k_topk(const float* __restrict__ xs, float* __restrict__ out_perm,
                       int* __restrict__ perm_i, int* __restrict__ maskarr) {
  __shared__ unsigned long long dv[1024];
  int b = blockIdx.x, t = threadIdx.x;
  for (int i = t; i < 1024; i += 512) {
    unsigned bits = __float_as_uint(xs[b * 1024 + i]);
    dv[i] = ((unsigned long long)bits << 32) | (unsigned)(N_ - 1 - i);
  }
  __syncthreads();
  for (int k2 = 2; k2 <= 1024; k2 <<= 1) {
    for (int j = k2 >> 1; j > 0; j >>= 1) {
      for (int i = t; i < 1024; i += 512) {
        int ixj = i ^ j;
        if (ixj > i) {
          unsigned long long a = dv[i], c = dv[ixj];
          bool dir = ((i & k2) == 0);              // true -> descending segment
          if ((a > c) != dir) { dv[i] = c; dv[ixj] = a; }
        }
      }
      __syncthreads();
    }
  }
  for (int r = t; r < K_; r += 512) {
    int idx = N_ - 1 - (int)(dv[r] & 0xFFFFFFFFull);
    int node = b * N_ + idx;
    int pos = b * K_ + r;
    out_perm[pos] = (float)node;    // output buffer is float32 view
    perm_i[pos] = node;
    maskarr[node] = pos;
  }
}

// ---- gather feat_p + wsrc/wdst dots (one wave per pooled row, fp32) ----
// Same XCD swizzle: 13120 blocks, graph spans 205 blocks -> XCD x gets graphs [8x,8x+8).
__global__ void k_gather(const float* __restrict__ feat, const int* __restrict__ perm_i,
                         const float* __restrict__ att, float* __restrict__ out_featp,
                         float* __restrict__ wsrc, float* __restrict__ wdst) {
  int g = blockIdx.x;
  int vb = (g & 7) * 1640 + (g >> 3);           // 13120 / 8
  int gid = vb * 256 + threadIdx.x;
  int p = gid >> 6, lane = gid & 63;
  int node = perm_i[p];
  float2 f = ((const float2*)feat)[(size_t)node * 64 + lane];
  ((float2*)out_featp)[(size_t)p * 64 + lane] = f;
  float s1 = f.x * att[2 * lane] + f.y * att[2 * lane + 1];
  float s2 = f.x * att[D_ + 2 * lane] + f.y * att[D_ + 2 * lane + 1];
#pragma unroll
  for (int off = 32; off > 0; off >>= 1) {
    s1 += __shfl_down(s1, off);
    s2 += __shfl_down(s2, off);
  }
  if (lane == 0) { wsrc[p] = s1; wdst[p] = s2; }
}

// ---- pooled-subgraph sparse entries DIRECTLY from the dst-CSR ----
// Column c = pooled node v = perm_i[c]; incoming edges are col[rowptr[v]..rowptr[v+1]).
// Filter by maskarr, dedupe inline, emit (nr, wsrc[nr], E) at fixed stride ST_.
// Replaces the R7 cnt2->scan->fill2->dedupe chain (5 dispatches -> 1).
__global__ void k_edges(const int* __restrict__ src, const float* __restrict__ e_feat,
                        const int* __restrict__ col, const int* __restrict__ rowptr,
                        const int* __restrict__ perm_i, const int* __restrict__ maskarr,
                        const float* __restrict__ wsrc, int* __restrict__ ucnt,
                        int* __restrict__ bidx, float2* __restrict__ bval) {
  int c = blockIdx.x * 256 + threadIdx.x;
  int v = perm_i[c];
  int r0 = rowptr[v], r1 = rowptr[v + 1];
  int base = c * ST_;
  int cnt = 0;
  for (int s = r0; s < r1; ++s) {
    int e = col[s];
    int nr = maskarr[src[e]];
    if (nr < 0) continue;                        // src not pooled
    float E = e_feat[e];                         // LAMB = 1
    bool dup = false;
    for (int k = 0; k < cnt; ++k) {
      if (bidx[base + k] == nr) { bval[base + k].y += E; dup = true; break; }
    }
    if (!dup && cnt < ST_) {
      bidx[base + cnt] = nr;
      bval[base + cnt] = make_float2(wsrc[nr], E);
      ++cnt;
    }
  }
  ucnt[c] = cnt;
}

// ---- per-graph sort of wsrc (desc) + prefix sums (512 threads) ----
__global__ void k_gsort(const float* __restrict__ wsrc, float* __restrict__ ws_sorted,
                        float* __restrict__ psum) {
  __shared__ float sv[1024];
  __shared__ float sc[1024];
  int b = blockIdx.x, t = threadIdx.x;
  for (int i = t; i < 1024; i += 512) sv[i] = (i < K_) ? wsrc[b * K_ + i] : -INFINITY;
  __syncthreads();
  for (int k2 = 2; k2 <= 1024; k2 <<= 1) {
    for (int j = k2 >> 1; j > 0; j >>= 1) {
      for (int i = t; i < 1024; i += 512) {
        int ixj = i ^ j;
        if (ixj > i) {
          float a = sv[i], c = sv[ixj];
          bool dir = ((i & k2) == 0);
          bool swapv = dir ? (c > a) : (a > c);
          if (swapv) { sv[i] = c; sv[ixj] = a; }
        }
      }
      __syncthreads();
    }
  }
  for (int i = t; i < 1024; i += 512) { ws_sorted[b * 1024 + i] = sv[i]; sc[i] = sv[i]; }
  __syncthreads();
  for (int off = 1; off < 1024; off <<= 1) {
    float tmp[2];
    for (int i = t, q = 0; i < 1024; i += 512, ++q) tmp[q] = (i >= off) ? sc[i - off] : 0.f;
    __syncthreads();
    for (int i = t, q = 0; i < 1024; i += 512, ++q) sc[i] += tmp[q];
    __syncthreads();
  }
  if (t == 0) psum[b * 1025] = 0.f;
  for (int i = t; i < 1024; i += 512) psum[b * 1025 + 1 + i] = sc[i];
}

// count of entries > thr in desc-sorted LDS array, searching index range [lo,hi)
__device__ __forceinline__ int cnt_gt_rng(const float* __restrict__ arr, float thr,
                                          int lo, int hi) {
  while (lo < hi) {
    int mid = (lo + hi) >> 1;
    if (arr[mid] > thr) lo = mid + 1; else hi = mid;
  }
  return lo;
}

// ---- tau per column via bisection on g(t) = sum max(z-t,0) = 1 ----
__global__ void __launch_bounds__(128) k_tau(
    const float* __restrict__ wdst,
    const float* __restrict__ ws_sorted, const float* __restrict__ psum,
    const int* __restrict__ ucnt, const float2* __restrict__ bval,
    float* __restrict__ tauv) {
  __shared__ float swss[1024];
  __shared__ float sps[1025];
  int b = blockIdx.x / CPB_;
  int chunk = blockIdx.x % CPB_;
  int t0 = threadIdx.x;
  for (int i = t0; i < 1024; i += 128) swss[i] = ws_sorted[b * 1024 + i];
  for (int i = t0; i < 1025; i += 128) sps[i] = psum[b * 1025 + i];
  __syncthreads();

  int j = chunk * CH_ + t0;
  if (j >= K_) return;
  int c = b * K_ + j;

  float wd = wdst[c];
  int p = cnt_gt_rng(swss, -wd, 0, K_);
  float psp = sps[p];
  int r0 = c * ST_, m = ucnt[c];

  float mz = lrelu(swss[0] + wd);
  for (int s = 0; s < m; ++s) {
    float2 v = bval[r0 + s];
    mz = fmaxf(mz, lrelu(v.x + wd) + v.y);       // E > 0 (e_feat=1, LAMB=1)
  }

  float lo = mz - 1.0f, hi = mz;                 // g(mz)=0<1, g(mz-1)>=1
  int nmin = 0, nmax = K_;                       // support-count bracket
  for (int it = 0; it < 22; ++it) {
    float t = 0.5f * (lo + hi);
    float wthr = (t >= 0.f ? t : 5.f * t) - wd;
    int n = cnt_gt_rng(swss, wthr, nmin, nmax);
    float bsum = (n <= p) ? (sps[n] + n * wd)
                          : (psp + p * wd + NEG_ * (sps[n] - psp + (n - p) * wd));
    float g = bsum - n * t;
    for (int s = 0; s < m; ++s) {
      float2 v = bval[r0 + s];
      float bse = lrelu(v.x + wd);
      g += fmaxf(bse + v.y - t, 0.f) - fmaxf(bse - t, 0.f);
    }
    if (g > 1.f) { lo = t; nmax = n; } else { hi = t; nmin = n; }
  }
  float t = lo;                                  // t <= tau*, bracket ~2.4e-7
  float wthr = (t >= 0.f ? t : 5.f * t) - wd;
  int n = cnt_gt_rng(swss, wthr, nmin, nmax);
  float S = (n <= p) ? (sps[n] + n * wd)
                     : (psp + p * wd + NEG_ * (sps[n] - psp + (n - p) * wd));
  int cc = n;
  for (int s = 0; s < m; ++s) {
    float2 v = bval[r0 + s];
    float bse = lrelu(v.x + wd);
    float zz = bse + v.y;
    if (v.x > wthr) { S -= bse; cc -= 1; }       // same predicate as cnt -> exact cancel
    if (zz > t)     { S += zz;  cc += 1; }
  }
  float tau = (cc < 1) ? (mz - 1.0f) : ((S - 1.0f) / (float)cc);
  tau = fminf(fmaxf(tau, mz - 1.0f), mz);        // true tau* in [mz-1, mz)
  tauv[c] = tau;
}

// ---- dense weights: float4 per thread (820 = 205*4), coalesced dwordx4 ----
__global__ void k_dense(const float* __restrict__ wsrc, const float* __restrict__ wdst,
                        const float* __restrict__ tauv, float* __restrict__ out_w) {
  int t = threadIdx.x;
  int j4 = t * 4;
  if (j4 >= K_) return;
  int row = blockIdx.x;                         // b*K + i
  int b = row / K_;
  const float4* wd4 = (const float4*)(wdst + b * K_);
  const float4* ta4 = (const float4*)(tauv + b * K_);
  float ws = wsrc[row];
  float4 wd = wd4[t];
  float4 ta = ta4[t];
  float4 o;
  float z;
  z = lrelu(ws + wd.x) - ta.x; o.x = (z > 1e-9f) ? z : 0.f;
  z = lrelu(ws + wd.y) - ta.y; o.y = (z > 1e-9f) ? z : 0.f;
  z = lrelu(ws + wd.z) - ta.z; o.z = (z > 1e-9f) ? z : 0.f;
  z = lrelu(ws + wd.w) - ta.w; o.w = (z > 1e-9f) ? z : 0.f;
  ((float4*)(out_w + (size_t)row * K_))[t] = o;
}

// ---- rewrite the edge-perturbed entries with the correct value ----
__global__ void k_fix(const float* __restrict__ wdst, const float* __restrict__ tauv,
                      const int* __restrict__ ucnt, const int* __restrict__ bidx,
                      const float2* __restrict__ bval, float* __restrict__ out_w) {
  int c = blockIdx.x * 256 + threadIdx.x;
  int b = c / K_;
  int j = c - b * K_;
  float wd = wdst[c], ta = tauv[c];
  int r0 = c * ST_, m = ucnt[c];
  for (int s = 0; s < m; ++s) {
    int nr = bidx[r0 + s];
    float2 v = bval[r0 + s];
    float z = lrelu(v.x + wd) + v.y;
    float o = z - ta;
    out_w[(size_t)nr * K_ + j] = (o > 1e-9f) ? o : 0.f;
  }
}

extern "C" void kernel_launch(void* const* d_in, const int* in_sizes, int n_in,
                              void* d_out, int out_size, void* d_ws, size_t ws_size,
                              hipStream_t stream) {
  const float* feat   = (const float*)d_in[0];
  const float* e_feat = (const float*)d_in[1];
  const float* W      = (const float*)d_in[2];
  const float* a      = (const float*)d_in[3];
  const float* att    = (const float*)d_in[4];
  const int*   src    = (const int*)d_in[5];
  const int*   dst    = (const int*)d_in[6];

  float* out_featp = (float*)d_out;                       // [BK*D]
  float* out_w     = out_featp + (size_t)BK_ * D_;        // [BK*K]
  float* out_perm  = out_w + (size_t)BK_ * K_;            // [BK]
  float* out_xs    = out_perm + BK_;                      // [NTOT]

  char* wsp = (char*)d_ws;
  auto carve = [&](size_t bytes) -> void* {
    void* pp = (void*)wsp;
    wsp += (bytes + 255) & ~(size_t)255;
    return pp;
  };
  float* waf       = (float*)carve((size_t)D_ * 4);
  float* wsrc      = (float*)carve((size_t)BK_ * 4);
  float* wdst      = (float*)carve((size_t)BK_ * 4);
  float* tauv      = (float*)carve((size_t)BK_ * 4);
  int* bidx        = (int*)carve((size_t)BK_ * ST_ * 4);
  float2* bval     = (float2*)carve((size_t)BK_ * ST_ * 8);
  int* ucnt        = (int*)carve((size_t)BK_ * 4);
  float* ws_sorted = (float*)carve((size_t)B_ * 1024 * 4);
  float* psum      = (float*)carve((size_t)B_ * 1025 * 4);
  int* rowptr      = (int*)carve((size_t)(NTOT_ + 1) * 4);
  int* col         = (int*)carve((size_t)ETOT_ * 4);
  int* perm_i      = (int*)carve((size_t)BK_ * 4);
  int* bsumA       = (int*)carve(64 * 4);
  size_t zbytes    = (size_t)NTOT_ * 3 * 4;
  int* zblk        = (int*)carve(zbytes);
  int* in_deg      = zblk;
  int* out_deg     = zblk + NTOT_;
  int* cursor      = zblk + 2 * NTOT_;
  int* maskarr     = (int*)carve((size_t)NTOT_ * 4);

  hipMemsetAsync(zblk, 0, zbytes, stream);
  hipMemsetAsync(maskarr, 0xFF, (size_t)NTOT_ * 4, stream);   // -1

  const int nbA = (NTOT_ + 1023) / 1024;   // 64

  k_wa<<<1, 128, 0, stream>>>(W, a, waf);
  k_deg<<<ETOT_ / 256, 256, 0, stream>>>(src, dst, out_deg, in_deg);
  k_scansum<<<nbA, 256, 0, stream>>>(in_deg, NTOT_, bsumA);
  k_scanout<<<nbA, 256, 0, stream>>>(in_deg, NTOT_, bsumA, rowptr);
  k_fillcsr<<<ETOT_ / 256, 256, 0, stream>>>(dst, rowptr, cursor, col);
  k_agg<<<NTOT_ / 4, 256, 0, stream>>>(feat, e_feat, src, col, rowptr, out_deg, in_deg,
                                       waf, out_xs);
  k_topk<<<B_, 512, 0, stream>>>(out_xs, out_perm, perm_i, maskarr);
  k_gather<<<BK_ / 4, 256, 0, stream>>>(feat, perm_i, att, out_featp, wsrc, wdst);
  k_edges<<<BK_ / 256, 256, 0, stream>>>(src, e_feat, col, rowptr, perm_i, maskarr,
                                         wsrc, ucnt, bidx, bval);
  k_gsort<<<B_, 512, 0, stream>>>(wsrc, ws_sorted, psum);
  k_tau<<<B_ * CPB_, 128, 0, stream>>>(wdst, ws_sorted, psum, ucnt, bval, tauv);
  k_dense<<<BK_, 256, 0, stream>>>(wsrc, wdst, tauv, out_w);
  k_fix<<<BK_ / 256, 256, 0, stream>>>(wdst, tauv, ucnt, bidx, bval, out_w);
}